// Round 3
// baseline (603.643 us; speedup 1.0000x reference)
//
#include <hip/hip_runtime.h>

#define N_NODES 100000
#define N_EDGES 1000000
#define IN_F 128
#define OUT_F 128
#define NUM_RELS 64
#define NB_SCAN ((N_NODES + 255) / 256)   // 391 blocks for the scan

// ---------------------------------------------------------------------------
// Kernel A: out[n][o] = bias[o] + sum_k h[n][k] * W[k][o]   (self-loop GEMM)
// 256 threads/block; block computes a 128-node x 128-out tile, 8x8 reg tile.
// ---------------------------------------------------------------------------
__global__ __launch_bounds__(256) void gemm_selfloop(
    const float* __restrict__ h, const float* __restrict__ W,
    const float* __restrict__ bias, float* __restrict__ out, int n_nodes)
{
    const int tid = threadIdx.x;
    const int ty = tid >> 4, tx = tid & 15;
    const int node0 = blockIdx.x * 128 + ty * 8;
    const int o0 = tx * 8;

    float acc[8][8];
#pragma unroll
    for (int j = 0; j < 8; ++j)
#pragma unroll
        for (int i = 0; i < 8; ++i) acc[j][i] = 0.f;

    int nidx[8];
#pragma unroll
    for (int j = 0; j < 8; ++j) {
        int n = node0 + j;
        nidx[j] = n < n_nodes ? n : (n_nodes - 1);
    }

    for (int k = 0; k < IN_F; k += 4) {
        float hsv[8][4];
#pragma unroll
        for (int j = 0; j < 8; ++j) {
            float4 hv = *reinterpret_cast<const float4*>(h + (size_t)nidx[j] * IN_F + k);
            *reinterpret_cast<float4*>(hsv[j]) = hv;
        }
#pragma unroll
        for (int kk = 0; kk < 4; ++kk) {
            const float* wrow = W + (size_t)(k + kk) * OUT_F + o0;
            float wr[8];
            *reinterpret_cast<float4*>(wr)     = *reinterpret_cast<const float4*>(wrow);
            *reinterpret_cast<float4*>(wr + 4) = *reinterpret_cast<const float4*>(wrow + 4);
#pragma unroll
            for (int j = 0; j < 8; ++j) {
                const float hk = hsv[j][kk];
#pragma unroll
                for (int i = 0; i < 8; ++i)
                    acc[j][i] = fmaf(hk, wr[i], acc[j][i]);
            }
        }
    }

    float br[8];
    *reinterpret_cast<float4*>(br)     = *reinterpret_cast<const float4*>(bias + o0);
    *reinterpret_cast<float4*>(br + 4) = *reinterpret_cast<const float4*>(bias + o0 + 4);

#pragma unroll
    for (int j = 0; j < 8; ++j) {
        int n = node0 + j;
        if (n < n_nodes) {
            float4 v0, v1;
            v0.x = acc[j][0] + br[0]; v0.y = acc[j][1] + br[1];
            v0.z = acc[j][2] + br[2]; v0.w = acc[j][3] + br[3];
            v1.x = acc[j][4] + br[4]; v1.y = acc[j][5] + br[5];
            v1.z = acc[j][6] + br[6]; v1.w = acc[j][7] + br[7];
            float* op = out + (size_t)n * OUT_F + o0;
            *reinterpret_cast<float4*>(op)     = v0;
            *reinterpret_cast<float4*>(op + 4) = v1;
        }
    }
}

// ---------------------------------------------------------------------------
// CSR build: histogram -> scan (3 kernels) -> fill (packed int4 meta in
// dst-grouped order: {src, rel, norm_bits, pad}).
// ---------------------------------------------------------------------------
__global__ __launch_bounds__(256) void hist_dst(
    const int* __restrict__ dst, int* __restrict__ cnt, int n_edges)
{
    int e = blockIdx.x * 256 + threadIdx.x;
    if (e < n_edges) atomicAdd(&cnt[dst[e]], 1);
}

__global__ __launch_bounds__(256) void block_sums(
    const int* __restrict__ cnt, int* __restrict__ part, int n)
{
    __shared__ int sdata[256];
    int i = blockIdx.x * 256 + threadIdx.x;
    sdata[threadIdx.x] = (i < n) ? cnt[i] : 0;
    __syncthreads();
    for (int s = 128; s > 0; s >>= 1) {
        if (threadIdx.x < s) sdata[threadIdx.x] += sdata[threadIdx.x + s];
        __syncthreads();
    }
    if (threadIdx.x == 0) part[blockIdx.x] = sdata[0];
}

// single block, 512 threads: exclusive scan of NB_SCAN (<=512) partials
__global__ __launch_bounds__(512) void scan_partials(int* __restrict__ part, int nb)
{
    __shared__ int buf[512];
    int tid = threadIdx.x;
    int v = (tid < nb) ? part[tid] : 0;
    buf[tid] = v;
    __syncthreads();
    for (int ofs = 1; ofs < 512; ofs <<= 1) {
        int t = (tid >= ofs) ? buf[tid - ofs] : 0;
        __syncthreads();
        buf[tid] += t;
        __syncthreads();
    }
    if (tid < nb) part[tid] = buf[tid] - v;   // exclusive
}

__global__ __launch_bounds__(256) void write_off(
    const int* __restrict__ cnt, const int* __restrict__ part,
    int* __restrict__ off, int* __restrict__ cur, int n, int n_edges)
{
    __shared__ int buf[256];
    int tid = threadIdx.x;
    int i = blockIdx.x * 256 + tid;
    int v = (i < n) ? cnt[i] : 0;
    buf[tid] = v;
    __syncthreads();
    for (int ofs = 1; ofs < 256; ofs <<= 1) {
        int t = (tid >= ofs) ? buf[tid - ofs] : 0;
        __syncthreads();
        buf[tid] += t;
        __syncthreads();
    }
    int excl = buf[tid] - v + part[blockIdx.x];
    if (i < n) { off[i] = excl; cur[i] = excl; }
    if (i == n - 1) off[n] = n_edges;
}

__global__ __launch_bounds__(256) void fill_csr(
    const int* __restrict__ src, const int* __restrict__ dst,
    const int* __restrict__ rel, const float* __restrict__ norm,
    int* __restrict__ cur, int4* __restrict__ emeta, int n_edges)
{
    int e = blockIdx.x * 256 + threadIdx.x;
    if (e < n_edges) {
        int d = dst[e];
        int p = atomicAdd(&cur[d], 1);
        int4 m;
        m.x = src[e];
        m.y = rel[e];
        m.z = __float_as_int(norm[e]);
        m.w = 0;
        emeta[p] = m;
    }
}

// ---------------------------------------------------------------------------
// Hot kernel v2: one wave per dst node, HALF-WAVE per edge (2 edges in
// flight per wave) x 2-slot unroll (4 edges per iteration).
// Lane (l = lane&31): block b = l>>1, quad jq = (l&1)*4 -> outputs 4*l..4*l+3.
// w loads are float4; cross-half reduce via shfl_xor(32); lower half does the
// fused  out = relu(out_selfloop + agg)  float4 RMW.
// ---------------------------------------------------------------------------
__global__ __launch_bounds__(256) void gather_nodes2(
    const float* __restrict__ h, const float* __restrict__ weight,
    const int* __restrict__ off, const int4* __restrict__ emeta,
    float* __restrict__ out, int n_nodes)
{
    const int lane = threadIdx.x & 63;
    const int wid  = threadIdx.x >> 6;
    const int d = blockIdx.x * 4 + wid;
    if (d >= n_nodes) return;

    const int hw = lane >> 5;        // half-wave: which edge slot
    const int l  = lane & 31;
    const int b  = l >> 1;           // BDD block 0..15
    const int jq = (l & 1) << 2;     // 0 or 4

    const int beg = off[d];
    const int end = off[d + 1];

    float4 aA = {0.f, 0.f, 0.f, 0.f};
    float4 aB = {0.f, 0.f, 0.f, 0.f};

    for (int j = beg; j < end; j += 4) {
        const int jA = j + hw;
        const int jB = j + 2 + hw;
        const bool vA = jA < end;
        const bool vB = jB < end;

        // independent meta loads (16B each) -> two parallel gather chains
        int4 mA = emeta[vA ? jA : beg];
        int4 mB = emeta[vB ? jB : beg];
        const float nmA = vA ? __int_as_float(mA.z) : 0.f;
        const float nmB = vB ? __int_as_float(mB.z) : 0.f;

        const float4* hrA = reinterpret_cast<const float4*>(h + (size_t)mA.x * IN_F + b * 8);
        const float4* hrB = reinterpret_cast<const float4*>(h + (size_t)mB.x * IN_F + b * 8);
        float hsA[8], hsB[8];
        *reinterpret_cast<float4*>(hsA)     = hrA[0];
        *reinterpret_cast<float4*>(hsA + 4) = hrA[1];
        *reinterpret_cast<float4*>(hsB)     = hrB[0];
        *reinterpret_cast<float4*>(hsB + 4) = hrB[1];

        const float* wA = weight + (size_t)mA.y * 1024 + b * 64 + jq;
        const float* wB = weight + (size_t)mB.y * 1024 + b * 64 + jq;

        float4 sA = {0.f, 0.f, 0.f, 0.f};
        float4 sB = {0.f, 0.f, 0.f, 0.f};
#pragma unroll
        for (int i = 0; i < 8; ++i) {
            float4 wvA = *reinterpret_cast<const float4*>(wA + i * 8);
            sA.x = fmaf(hsA[i], wvA.x, sA.x);
            sA.y = fmaf(hsA[i], wvA.y, sA.y);
            sA.z = fmaf(hsA[i], wvA.z, sA.z);
            sA.w = fmaf(hsA[i], wvA.w, sA.w);
            float4 wvB = *reinterpret_cast<const float4*>(wB + i * 8);
            sB.x = fmaf(hsB[i], wvB.x, sB.x);
            sB.y = fmaf(hsB[i], wvB.y, sB.y);
            sB.z = fmaf(hsB[i], wvB.z, sB.z);
            sB.w = fmaf(hsB[i], wvB.w, sB.w);
        }
        aA.x = fmaf(sA.x, nmA, aA.x);
        aA.y = fmaf(sA.y, nmA, aA.y);
        aA.z = fmaf(sA.z, nmA, aA.z);
        aA.w = fmaf(sA.w, nmA, aA.w);
        aB.x = fmaf(sB.x, nmB, aB.x);
        aB.y = fmaf(sB.y, nmB, aB.y);
        aB.z = fmaf(sB.z, nmB, aB.z);
        aB.w = fmaf(sB.w, nmB, aB.w);
    }

    float4 a;
    a.x = aA.x + aB.x;
    a.y = aA.y + aB.y;
    a.z = aA.z + aB.z;
    a.w = aA.w + aB.w;

    // reduce across the two half-waves (edge slots)
    a.x += __shfl_xor(a.x, 32);
    a.y += __shfl_xor(a.y, 32);
    a.z += __shfl_xor(a.z, 32);
    a.w += __shfl_xor(a.w, 32);

    if (hw == 0) {
        float4* op = reinterpret_cast<float4*>(out + (size_t)d * OUT_F) + l;
        float4 base = *op;
        float4 res;
        res.x = fmaxf(base.x + a.x, 0.f);
        res.y = fmaxf(base.y + a.y, 0.f);
        res.z = fmaxf(base.z + a.z, 0.f);
        res.w = fmaxf(base.w + a.w, 0.f);
        *op = res;
    }
}

extern "C" void kernel_launch(void* const* d_in, const int* in_sizes, int n_in,
                              void* d_out, int out_size, void* d_ws, size_t ws_size,
                              hipStream_t stream)
{
    const float* h      = (const float*)d_in[0];
    const float* norm   = (const float*)d_in[1];
    const float* weight = (const float*)d_in[2];
    const float* loop_w = (const float*)d_in[3];
    const float* bias   = (const float*)d_in[4];
    const int*   src    = (const int*)d_in[5];
    const int*   dst    = (const int*)d_in[6];
    const int*   rel    = (const int*)d_in[7];
    float* out = (float*)d_out;

    // ws layout: cnt[N], off[N+1], cur[N], part[512], emeta[E] (int4) ~17.2MB
    char* wsb = (char*)d_ws;
    int*  cnt   = (int*)wsb;  wsb += sizeof(int) * N_NODES;
    int*  off   = (int*)wsb;  wsb += sizeof(int) * (N_NODES + 1);
    int*  cur   = (int*)wsb;  wsb += sizeof(int) * N_NODES;
    int*  part  = (int*)wsb;  wsb += sizeof(int) * 512;
    // align to 16B for int4
    wsb = (char*)(((uintptr_t)wsb + 15) & ~(uintptr_t)15);
    int4* emeta = (int4*)wsb; wsb += sizeof(int4) * N_EDGES;

    hipMemsetAsync(cnt, 0, sizeof(int) * N_NODES, stream);

    const int egrid = (N_EDGES + 255) / 256;
    hist_dst<<<egrid, 256, 0, stream>>>(dst, cnt, N_EDGES);
    block_sums<<<NB_SCAN, 256, 0, stream>>>(cnt, part, N_NODES);
    scan_partials<<<1, 512, 0, stream>>>(part, NB_SCAN);
    write_off<<<NB_SCAN, 256, 0, stream>>>(cnt, part, off, cur, N_NODES, N_EDGES);
    fill_csr<<<egrid, 256, 0, stream>>>(src, dst, rel, norm, cur, emeta, N_EDGES);

    // self-loop GEMM (bias included) -> out
    gemm_selfloop<<<(N_NODES + 127) / 128, 256, 0, stream>>>(h, loop_w, bias, out, N_NODES);
    // per-dst register accumulation + fused ReLU
    gather_nodes2<<<(N_NODES + 3) / 4, 256, 0, stream>>>(
        h, weight, off, emeta, out, N_NODES);
}

// Round 4
// 366.123 us; speedup vs baseline: 1.6487x; 1.6487x over previous
//
#include <hip/hip_runtime.h>

#define N_NODES 100000
#define N_EDGES 1000000
#define IN_F 128
#define OUT_F 128
#define NUM_RELS 64
#define NB_SCAN ((N_NODES + 255) / 256)   // 391 blocks for the scan

// ---------------------------------------------------------------------------
// Kernel A: out[n][o] = bias[o] + sum_k h[n][k] * W[k][o]   (self-loop GEMM)
// ---------------------------------------------------------------------------
__global__ __launch_bounds__(256) void gemm_selfloop(
    const float* __restrict__ h, const float* __restrict__ W,
    const float* __restrict__ bias, float* __restrict__ out, int n_nodes)
{
    const int tid = threadIdx.x;
    const int ty = tid >> 4, tx = tid & 15;
    const int node0 = blockIdx.x * 128 + ty * 8;
    const int o0 = tx * 8;

    float acc[8][8];
#pragma unroll
    for (int j = 0; j < 8; ++j)
#pragma unroll
        for (int i = 0; i < 8; ++i) acc[j][i] = 0.f;

    int nidx[8];
#pragma unroll
    for (int j = 0; j < 8; ++j) {
        int n = node0 + j;
        nidx[j] = n < n_nodes ? n : (n_nodes - 1);
    }

    for (int k = 0; k < IN_F; k += 4) {
        float hsv[8][4];
#pragma unroll
        for (int j = 0; j < 8; ++j) {
            float4 hv = *reinterpret_cast<const float4*>(h + (size_t)nidx[j] * IN_F + k);
            *reinterpret_cast<float4*>(hsv[j]) = hv;
        }
#pragma unroll
        for (int kk = 0; kk < 4; ++kk) {
            const float* wrow = W + (size_t)(k + kk) * OUT_F + o0;
            float wr[8];
            *reinterpret_cast<float4*>(wr)     = *reinterpret_cast<const float4*>(wrow);
            *reinterpret_cast<float4*>(wr + 4) = *reinterpret_cast<const float4*>(wrow + 4);
#pragma unroll
            for (int j = 0; j < 8; ++j) {
                const float hk = hsv[j][kk];
#pragma unroll
                for (int i = 0; i < 8; ++i)
                    acc[j][i] = fmaf(hk, wr[i], acc[j][i]);
            }
        }
    }

    float br[8];
    *reinterpret_cast<float4*>(br)     = *reinterpret_cast<const float4*>(bias + o0);
    *reinterpret_cast<float4*>(br + 4) = *reinterpret_cast<const float4*>(bias + o0 + 4);

#pragma unroll
    for (int j = 0; j < 8; ++j) {
        int n = node0 + j;
        if (n < n_nodes) {
            float4 v0, v1;
            v0.x = acc[j][0] + br[0]; v0.y = acc[j][1] + br[1];
            v0.z = acc[j][2] + br[2]; v0.w = acc[j][3] + br[3];
            v1.x = acc[j][4] + br[4]; v1.y = acc[j][5] + br[5];
            v1.z = acc[j][6] + br[6]; v1.w = acc[j][7] + br[7];
            float* op = out + (size_t)n * OUT_F + o0;
            *reinterpret_cast<float4*>(op)     = v0;
            *reinterpret_cast<float4*>(op + 4) = v1;
        }
    }
}

// ---------------------------------------------------------------------------
// CSR build: histogram -> scan -> fill (packed int4 meta {src, rel, norm, 0}).
// ---------------------------------------------------------------------------
__global__ __launch_bounds__(256) void hist_dst(
    const int* __restrict__ dst, int* __restrict__ cnt, int n_edges)
{
    int e = blockIdx.x * 256 + threadIdx.x;
    if (e < n_edges) atomicAdd(&cnt[dst[e]], 1);
}

__global__ __launch_bounds__(256) void block_sums(
    const int* __restrict__ cnt, int* __restrict__ part, int n)
{
    __shared__ int sdata[256];
    int i = blockIdx.x * 256 + threadIdx.x;
    sdata[threadIdx.x] = (i < n) ? cnt[i] : 0;
    __syncthreads();
    for (int s = 128; s > 0; s >>= 1) {
        if (threadIdx.x < s) sdata[threadIdx.x] += sdata[threadIdx.x + s];
        __syncthreads();
    }
    if (threadIdx.x == 0) part[blockIdx.x] = sdata[0];
}

__global__ __launch_bounds__(512) void scan_partials(int* __restrict__ part, int nb)
{
    __shared__ int buf[512];
    int tid = threadIdx.x;
    int v = (tid < nb) ? part[tid] : 0;
    buf[tid] = v;
    __syncthreads();
    for (int ofs = 1; ofs < 512; ofs <<= 1) {
        int t = (tid >= ofs) ? buf[tid - ofs] : 0;
        __syncthreads();
        buf[tid] += t;
        __syncthreads();
    }
    if (tid < nb) part[tid] = buf[tid] - v;   // exclusive
}

__global__ __launch_bounds__(256) void write_off(
    const int* __restrict__ cnt, const int* __restrict__ part,
    int* __restrict__ off, int* __restrict__ cur, int n, int n_edges)
{
    __shared__ int buf[256];
    int tid = threadIdx.x;
    int i = blockIdx.x * 256 + tid;
    int v = (i < n) ? cnt[i] : 0;
    buf[tid] = v;
    __syncthreads();
    for (int ofs = 1; ofs < 256; ofs <<= 1) {
        int t = (tid >= ofs) ? buf[tid - ofs] : 0;
        __syncthreads();
        buf[tid] += t;
        __syncthreads();
    }
    int excl = buf[tid] - v + part[blockIdx.x];
    if (i < n) { off[i] = excl; cur[i] = excl; }
    if (i == n - 1) off[n] = n_edges;
}

__global__ __launch_bounds__(256) void fill_csr(
    const int* __restrict__ src, const int* __restrict__ dst,
    const int* __restrict__ rel, const float* __restrict__ norm,
    int* __restrict__ cur, int4* __restrict__ emeta, int n_edges)
{
    int e = blockIdx.x * 256 + threadIdx.x;
    if (e < n_edges) {
        int d = dst[e];
        int p = atomicAdd(&cur[d], 1);
        int4 m;
        m.x = src[e];
        m.y = rel[e];
        m.z = __float_as_int(norm[e]);
        m.w = 0;
        emeta[p] = m;
    }
}

// ---------------------------------------------------------------------------
// Prep: weight f32 -> bf16x2-packed, XOR-swizzled layout, one 512-dword tile
// per relation. LDS word wp (within tile) holds logical (b, i = ii^(b&7), q)
// where wp = b*32 + ii*4 + q; packed pair = outputs (2q, 2q+1). RNE rounding.
// ---------------------------------------------------------------------------
__global__ __launch_bounds__(256) void prep_wbf16(
    const float* __restrict__ weight, uint32_t* __restrict__ wsw)
{
    int t = blockIdx.x * 256 + threadIdx.x;          // 0 .. 64*512-1
    if (t >= NUM_RELS * 512) return;
    int r  = t >> 9;
    int wp = t & 511;
    int b  = wp >> 5;
    int ii = (wp >> 2) & 7;
    int q  = wp & 3;
    int i  = ii ^ (b & 7);
    const float* s = weight + (size_t)r * 1024 + b * 64 + i * 8 + q * 2;
    uint32_t u0 = __float_as_uint(s[0]);
    uint32_t u1 = __float_as_uint(s[1]);
    uint32_t lo = (u0 + 0x7fffu + ((u0 >> 16) & 1u)) >> 16;   // RNE bf16
    uint32_t hi = (u1 + 0x7fffu + ((u1 >> 16) & 1u)) >> 16;
    wsw[t] = lo | (hi << 16);
}

// ---------------------------------------------------------------------------
// Hot kernel v3: one wave per dst node. Per edge, stage the 2KB bf16 w-tile
// via 2 coalesced uint4 loads/lane -> ds_write_b128 (linear) -> 8 swizzled
// ds_read_b32 (2-way bank aliasing = free). 2-deep register pipeline on
// meta/w/h so next-edge loads overlap current-edge LDS compute.
// lane: b = lane>>2 (BDD block), jp = (lane&3)*2 (output pair).
// ---------------------------------------------------------------------------
__global__ __launch_bounds__(256) void gather_nodes3(
    const float* __restrict__ h, const uint32_t* __restrict__ wsw,
    const int* __restrict__ off, const int4* __restrict__ emeta,
    float* __restrict__ out, int n_nodes)
{
    __shared__ uint32_t lds[4][512];

    const int lane = threadIdx.x & 63;
    const int wid  = threadIdx.x >> 6;
    const int d = blockIdx.x * 4 + wid;
    if (d >= n_nodes) return;

    const int b  = lane >> 2;
    const int q  = lane & 3;          // output pair index
    const int jp = q << 1;

    uint32_t* slot = lds[wid];
    uint4* slot4 = reinterpret_cast<uint4*>(slot);
    const uint4* wsw4 = reinterpret_cast<const uint4*>(wsw);

    // per-lane swizzled LDS word offsets for i = 0..7
    int woff[8];
#pragma unroll
    for (int i = 0; i < 8; ++i)
        woff[i] = b * 32 + ((i ^ (b & 7)) << 2) + q;

    const int beg = off[d];
    const int end = off[d + 1];

    float a0 = 0.f, a1 = 0.f;

    if (beg < end) {
        int4 me = emeta[beg];
        int j1 = (beg + 1 < end) ? beg + 1 : beg;
        int4 mn = emeta[j1];

        uint4 wa = wsw4[me.y * 128 + lane];
        uint4 wb = wsw4[me.y * 128 + 64 + lane];
        const float4* hr = reinterpret_cast<const float4*>(h + (size_t)me.x * IN_F + b * 8);
        float4 ha = hr[0], hb = hr[1];

        for (int j = beg; j < end; ++j) {
            // prefetch meta two ahead, w/h one ahead (clamped, wave-uniform)
            int j2 = (j + 2 < end) ? j + 2 : end - 1;
            int4 mnn = emeta[j2];
            uint4 wna = wsw4[mn.y * 128 + lane];
            uint4 wnb = wsw4[mn.y * 128 + 64 + lane];
            const float4* hrn = reinterpret_cast<const float4*>(h + (size_t)mn.x * IN_F + b * 8);
            float4 hna = hrn[0], hnb = hrn[1];

            // stage current w tile (linear, conflict-free b128 writes)
            slot4[lane]      = wa;
            slot4[64 + lane] = wb;

            float hs[8];
            *reinterpret_cast<float4*>(hs)     = ha;
            *reinterpret_cast<float4*>(hs + 4) = hb;

            float m0 = 0.f, m1 = 0.f;
#pragma unroll
            for (int i = 0; i < 8; ++i) {
                uint32_t pk = slot[woff[i]];
                float wlo = __uint_as_float(pk << 16);
                float whi = __uint_as_float(pk & 0xffff0000u);
                m0 = fmaf(hs[i], wlo, m0);
                m1 = fmaf(hs[i], whi, m1);
            }
            const float nm = __int_as_float(me.z);
            a0 = fmaf(m0, nm, a0);
            a1 = fmaf(m1, nm, a1);

            // rotate pipeline
            me = mn; mn = mnn;
            wa = wna; wb = wnb;
            ha = hna; hb = hnb;
        }
    }

    // fused  out = relu(selfloop + agg)
    float2* op = reinterpret_cast<float2*>(out + (size_t)d * OUT_F + b * 8 + jp);
    float2 base = *op;
    float2 res;
    res.x = fmaxf(base.x + a0, 0.f);
    res.y = fmaxf(base.y + a1, 0.f);
    *op = res;
}

extern "C" void kernel_launch(void* const* d_in, const int* in_sizes, int n_in,
                              void* d_out, int out_size, void* d_ws, size_t ws_size,
                              hipStream_t stream)
{
    const float* h      = (const float*)d_in[0];
    const float* norm   = (const float*)d_in[1];
    const float* weight = (const float*)d_in[2];
    const float* loop_w = (const float*)d_in[3];
    const float* bias   = (const float*)d_in[4];
    const int*   src    = (const int*)d_in[5];
    const int*   dst    = (const int*)d_in[6];
    const int*   rel    = (const int*)d_in[7];
    float* out = (float*)d_out;

    // ws layout: cnt[N], off[N+1], cur[N], part[512], wsw[64*512 u32],
    // emeta[E] int4  -> ~17.3 MB
    char* wsb = (char*)d_ws;
    int*  cnt   = (int*)wsb;  wsb += sizeof(int) * N_NODES;
    int*  off   = (int*)wsb;  wsb += sizeof(int) * (N_NODES + 1);
    int*  cur   = (int*)wsb;  wsb += sizeof(int) * N_NODES;
    int*  part  = (int*)wsb;  wsb += sizeof(int) * 512;
    wsb = (char*)(((uintptr_t)wsb + 15) & ~(uintptr_t)15);
    uint32_t* wsw = (uint32_t*)wsb; wsb += sizeof(uint32_t) * NUM_RELS * 512;
    int4* emeta = (int4*)wsb; wsb += sizeof(int4) * N_EDGES;

    hipMemsetAsync(cnt, 0, sizeof(int) * N_NODES, stream);

    const int egrid = (N_EDGES + 255) / 256;
    hist_dst<<<egrid, 256, 0, stream>>>(dst, cnt, N_EDGES);
    block_sums<<<NB_SCAN, 256, 0, stream>>>(cnt, part, N_NODES);
    scan_partials<<<1, 512, 0, stream>>>(part, NB_SCAN);
    write_off<<<NB_SCAN, 256, 0, stream>>>(cnt, part, off, cur, N_NODES, N_EDGES);
    fill_csr<<<egrid, 256, 0, stream>>>(src, dst, rel, norm, cur, emeta, N_EDGES);
    prep_wbf16<<<(NUM_RELS * 512 + 255) / 256, 256, 0, stream>>>(weight, wsw);

    gemm_selfloop<<<(N_NODES + 127) / 128, 256, 0, stream>>>(h, loop_w, bias, out, N_NODES);
    gather_nodes3<<<(N_NODES + 3) / 4, 256, 0, stream>>>(
        h, wsw, off, emeta, out, N_NODES);
}